// Round 13
// baseline (216.309 us; speedup 1.0000x reference)
//
#include <hip/hip_runtime.h>
#include <hip/hip_fp16.h>

// Problem constants
#define BB 4
#define TT 16
#define HH 512
#define WW 512
#define SP 528                        // padded row stride (halfs) for the f16 inter-pass buffer

// Tile: 256 threads = 4 waves; output 64x64. Wave wv owns rows 16wv..16wv+15 x 64 cols
// (4 col strips of 16 -> 4 independent accumulators = ILP).
#define BTILE 64
#define ROWB 160                      // LDS plane row stride bytes (80 halfs, exact fit)
#define PROWS 80                      // 64 + 2*8 halo
#define PLANE_STRIDE 13312            // 13 x 1024B chunks (12800 used) - DMA-chunk aligned
#define LDS_BYTES (3 * PLANE_STRIDE)  // 39936 B

typedef _Float16 half8 __attribute__((ext_vector_type(8)));
typedef float f32x4 __attribute__((ext_vector_type(4)));

constexpr int kR[9] = {-8, -4, -2, -1, 0, 1, 2, 4, 8};   // merged tap rows

__device__ __forceinline__ int reflect_idx(int q, int n) {
    q = abs(q);
    if (q >= n) q = 2 * n - 2 - q;
    return q;
}

__device__ __forceinline__ void async_cp16(const __half* g, char* l) {
#if __has_builtin(__builtin_amdgcn_global_load_lds)
    __builtin_amdgcn_global_load_lds(
        (const __attribute__((address_space(1))) unsigned int*)g,
        (__attribute__((address_space(3))) unsigned int*)l, 16, 0, 0);
#else
    *reinterpret_cast<uint4*>(l) = *reinterpret_cast<const uint4*>(g);
#endif
}

// 27 B-fragment matrices (ch x tap-row), 32x16 f16 banded-Toeplitz in MFMA fragment order:
// frag[(ch*9+ri)*64 + lane][e], B[k][j], j=lane&15, k=8*(lane>>4)+e, val=merged_w[ch][r][k-8-j].
// Combined bias stored as float at halfs[27*64*8].
__global__ void pack_bfrag(const float* __restrict__ w1, const float* __restrict__ b1,
                           const float* __restrict__ w2, const float* __restrict__ b2,
                           const float* __restrict__ w3, const float* __restrict__ b3,
                           const float* __restrict__ sa, const float* __restrict__ sb,
                           const float* __restrict__ sc_, __half* __restrict__ bfrag) {
    const int tid = threadIdx.x;
    float s[3] = {sa[0], sb[0], sc_[0]};
    const float* wp[3] = {w1, w2, w3};
    for (int idx = tid; idx < 27 * 64; idx += blockDim.x) {
        int mat = idx >> 6;
        int lane = idx & 63;
        int ch = mat / 9, ri = mat % 9;
        int r = kR[ri];
        int j = lane & 15, kg = lane >> 4;
        union { __half h[8]; uint4 u; } v;
#pragma unroll
        for (int e = 0; e < 8; ++e) {
            int k = kg * 8 + e;
            int c = k - 8 - j;
            float a = 0.f;
            if (c >= -8 && c <= 8) {
                for (int b = 0; b < 3; ++b) {
                    int d = 1 << b;
                    if (r % d == 0 && c % d == 0) {
                        int rd = r / d, cd = c / d;
                        if (rd >= -2 && rd <= 2 && cd >= -2 && cd <= 2)
                            a += s[b] * wp[b][ch * 25 + (rd + 2) * 5 + (cd + 2)];
                    }
                }
            }
            v.h[e] = __float2half(a);
        }
        *reinterpret_cast<uint4*>(bfrag + idx * 8) = v.u;
    }
    if (tid == 0)
        *reinterpret_cast<float*>(bfrag + 27 * 64 * 8) = s[0] * b1[0] + s[1] * b2[0] + s[2] * b3[0];
}

// PASS 1: in = f32 x (unpadded), out = f16 ypad (stride SP, reflect-padded cols)
// PASS 2: in = f16 ypad,         out = f32 z   (unpadded)
template <int PASS>
__global__ __launch_bounds__(256, 2) void conv_mfma(const void* __restrict__ xin,
                                                    void* __restrict__ outp,
                                                    const __half* __restrict__ bfrag) {
    __shared__ char lds[LDS_BYTES];

    const int bt = blockIdx.z;
    const int t  = bt % TT;
    const int h0 = blockIdx.y * BTILE;
    const int w0 = blockIdx.x * BTILE;
    const int tid = threadIdx.x;
    const int lane = tid & 63;
    const int wv = tid >> 6;                  // wave id 0..3 = row strip

    const int tprev = (t == 0) ? 1 : t - 1;
    const int tnext = (t == TT - 1) ? TT - 2 : t + 1;
    const int bbase = (bt / TT) * TT;

    // ---- Load ALL 27 B-fragments and PIN them in VGPRs (asm sink-blocker).
    // Per-component scalar ties: each "+v" operand is ONE 32-bit VGPR (the
    // r12 uint4 tie was an unsupported multi-reg indirect operand).
    union { uint4 u; half8 h; } braw[27];
#pragma unroll
    for (int m = 0; m < 27; ++m) {
        braw[m].u = *reinterpret_cast<const uint4*>(bfrag + m * 512 + lane * 8);
        asm volatile("" : "+v"(braw[m].u.x), "+v"(braw[m].u.y),
                          "+v"(braw[m].u.z), "+v"(braw[m].u.w));
    }
    const float bias = *reinterpret_cast<const float*>(bfrag + 27 * 64 * 8);

    if constexpr (PASS == 1) {
        // ---- manual staging: f32 global -> f16 LDS, full reflect ----
        const float* x = (const float*)xin;
        const size_t fs = (size_t)HH * WW;
        const float* f0 = x + (size_t)(bbase + tprev) * fs;
        const float* f1 = x + (size_t)bt * fs;
        const float* f2 = x + (size_t)(bbase + tnext) * fs;
        for (int k2 = tid; k2 < 2400; k2 += 256) {
            int ch  = k2 / 800;
            int rem = k2 - ch * 800;
            int row = rem / 10;
            int c8  = rem - row * 10;
            const float* src = (ch == 0) ? f0 : (ch == 1) ? f1 : f2;
            int gh = reflect_idx(h0 - 8 + row, HH);
            int gb = w0 - 8 + c8 * 8;
            const float* rp = src + (size_t)gh * WW;
            union { __half h[8]; uint4 u; } cv;
            if (gb >= 0 && gb + 7 < WW) {
                const float4 v0 = *reinterpret_cast<const float4*>(rp + gb);
                const float4 v1 = *reinterpret_cast<const float4*>(rp + gb + 4);
                cv.h[0] = __float2half(v0.x); cv.h[1] = __float2half(v0.y);
                cv.h[2] = __float2half(v0.z); cv.h[3] = __float2half(v0.w);
                cv.h[4] = __float2half(v1.x); cv.h[5] = __float2half(v1.y);
                cv.h[6] = __float2half(v1.z); cv.h[7] = __float2half(v1.w);
            } else {
#pragma unroll
                for (int e = 0; e < 8; ++e)
                    cv.h[e] = __float2half(rp[reflect_idx(gb + e, WW)]);
            }
            *reinterpret_cast<uint4*>(lds + ch * PLANE_STRIDE + row * ROWB + c8 * 16) = cv.u;
        }
        __syncthreads();
    } else {
        // ---- DMA staging: f16 padded global -> LDS via global_load_lds ----
        const __half* y = (const __half*)xin;
        const size_t fsP = (size_t)HH * SP;
        const __half* f0 = y + (size_t)(bbase + tprev) * fsP;
        const __half* f1 = y + (size_t)bt * fsP;
        const __half* f2 = y + (size_t)(bbase + tnext) * fsP;
        for (int c = wv; c < 39; c += 4) {       // 13 chunks x 3 planes, wave-uniform
            int plane = c / 13;
            int sub   = c - plane * 13;
            const __half* srcf = (plane == 0) ? f0 : (plane == 1) ? f1 : f2;
            int byt = sub * 1024 + lane * 16;
            if (byt < PROWS * ROWB) {            // tail lanes of chunk 12 masked
                int row  = byt / ROWB;
                int colh = (byt - row * ROWB) >> 1;
                int gh = reflect_idx(h0 - 8 + row, HH);
                const __half* g = srcf + (size_t)gh * SP + (w0 + colh);  // pad +8 == halo -8
                async_cp16(g, lds + plane * PLANE_STRIDE + byt);
            }
        }
        asm volatile("s_waitcnt vmcnt(0)" ::: "memory");
        __syncthreads();
    }

    // ---- MFMA compute: pure ds_read(base+imm) -> MFMA, B resident in VGPRs ----
    f32x4 acc0 = {bias, bias, bias, bias};
    f32x4 acc1 = acc0, acc2 = acc0, acc3 = acc0;

    const int i16 = lane & 15;
    const int kg  = lane >> 4;
    const char* aB0 = lds + (16 * wv + i16) * ROWB + kg * 16;

#pragma unroll
    for (int ch = 0; ch < 3; ++ch) {
#pragma unroll
        for (int ri = 0; ri < 9; ++ri) {
            const char* ar = aB0 + ch * PLANE_STRIDE + (kR[ri] + 8) * ROWB;  // literal imms
            half8 a0 = *reinterpret_cast<const half8*>(ar);
            half8 a1 = *reinterpret_cast<const half8*>(ar + 32);
            half8 a2 = *reinterpret_cast<const half8*>(ar + 64);
            half8 a3 = *reinterpret_cast<const half8*>(ar + 96);
            const half8 b = braw[ch * 9 + ri].h;
            __builtin_amdgcn_s_setprio(1);
            acc0 = __builtin_amdgcn_mfma_f32_16x16x32_f16(a0, b, acc0, 0, 0, 0);
            acc1 = __builtin_amdgcn_mfma_f32_16x16x32_f16(a1, b, acc1, 0, 0, 0);
            acc2 = __builtin_amdgcn_mfma_f32_16x16x32_f16(a2, b, acc2, 0, 0, 0);
            acc3 = __builtin_amdgcn_mfma_f32_16x16x32_f16(a3, b, acc3, 0, 0, 0);
            __builtin_amdgcn_s_setprio(0);
        }
    }

    // ---- Epilogue: tanh; C layout col=lane&15, row=(lane>>4)*4+reg ----
    if constexpr (PASS == 1) {
        __half* yp = (__half*)outp + (size_t)bt * HH * SP;
#pragma unroll
        for (int sc = 0; sc < 4; ++sc) {
            f32x4 a = (sc == 0) ? acc0 : (sc == 1) ? acc1 : (sc == 2) ? acc2 : acc3;
            const int wcol = w0 + sc * 16 + i16;
#pragma unroll
            for (int v2 = 0; v2 < 4; ++v2) {
                float z = a[v2];
                float e = __expf(2.0f * z);
                z = 1.0f - 2.0f / (e + 1.0f);
                __half hz = __float2half(z);
                __half* rb = yp + (size_t)(h0 + 16 * wv + kg * 4 + v2) * SP;
                rb[8 + wcol] = hz;
                if (wcol >= 1 && wcol <= 8)          rb[8 - wcol] = hz;       // left mirror
                else if (wcol >= 503 && wcol <= 510) rb[1030 - wcol] = hz;    // right mirror
            }
        }
    } else {
        float* dst = (float*)outp + (size_t)bt * HH * WW
                   + (size_t)(h0 + 16 * wv + kg * 4) * WW + (w0 + i16);
#pragma unroll
        for (int sc = 0; sc < 4; ++sc) {
            f32x4 a = (sc == 0) ? acc0 : (sc == 1) ? acc1 : (sc == 2) ? acc2 : acc3;
#pragma unroll
            for (int v2 = 0; v2 < 4; ++v2) {
                float z = a[v2];
                float e = __expf(2.0f * z);
                dst[(size_t)v2 * WW + sc * 16] = 1.0f - 2.0f / (e + 1.0f);
            }
        }
    }
}

extern "C" void kernel_launch(void* const* d_in, const int* in_sizes, int n_in,
                              void* d_out, int out_size, void* d_ws, size_t ws_size,
                              hipStream_t stream) {
    const float* x = (const float*)d_in[0];
    char* ws = (char*)d_ws;
    __half* bf1  = (__half*)ws;                        // 27.7 KB
    __half* bf2  = (__half*)(ws + 32768);              // 27.7 KB
    __half* ypad = (__half*)(ws + 65536);              // 64 x 512 x 528 f16 = 34.6 MB

    pack_bfrag<<<1, 256, 0, stream>>>((const float*)d_in[1], (const float*)d_in[2],
                                      (const float*)d_in[3], (const float*)d_in[4],
                                      (const float*)d_in[5], (const float*)d_in[6],
                                      (const float*)d_in[7], (const float*)d_in[8],
                                      (const float*)d_in[9], bf1);
    pack_bfrag<<<1, 256, 0, stream>>>((const float*)d_in[10], (const float*)d_in[11],
                                      (const float*)d_in[12], (const float*)d_in[13],
                                      (const float*)d_in[14], (const float*)d_in[15],
                                      (const float*)d_in[16], (const float*)d_in[17],
                                      (const float*)d_in[18], bf2);

    dim3 grid(WW / BTILE, HH / BTILE, BB * TT);   // 8 x 8 x 64
    conv_mfma<1><<<grid, 256, 0, stream>>>(x, ypad, bf1);
    conv_mfma<2><<<grid, 256, 0, stream>>>(ypad, d_out, bf2);
}

// Round 14
// 175.889 us; speedup vs baseline: 1.2298x; 1.2298x over previous
//
#include <hip/hip_runtime.h>
#include <hip/hip_fp16.h>

// Problem constants
#define BB 4
#define TT 16
#define HH 512
#define WW 512
#define SP 528                        // padded row stride (halfs) of the f16 inter-pass buffer

// Tile: 256 threads = 4 waves; output 64x64. Wave wv owns rows 16wv..16wv+15 x 64 cols.
// LDS: TWO single-channel ping-pong buffers -> stage(ch+1) overlaps compute(ch).
#define BTILE 64
#define ROWB 160                      // buffer row stride bytes (80 halfs, exact window)
#define PROWS 80                      // 64 + 2*8 halo rows
#define PLANE_BYTES (PROWS * ROWB)    // 12800 used
#define PLANE_STRIDE 13312            // 13 x 1024B DMA chunks
#define LDS_BYTES (2 * PLANE_STRIDE)  // 26624 B -> 5-6 blocks/CU

typedef _Float16 half8 __attribute__((ext_vector_type(8)));
typedef float f32x4 __attribute__((ext_vector_type(4)));

constexpr int kR[9] = {-8, -4, -2, -1, 0, 1, 2, 4, 8};   // merged tap rows

__device__ __forceinline__ int reflect_idx(int q, int n) {
    q = abs(q);
    if (q >= n) q = 2 * n - 2 - q;
    return q;
}

__device__ __forceinline__ void async_cp16(const __half* g, char* l) {
#if __has_builtin(__builtin_amdgcn_global_load_lds)
    __builtin_amdgcn_global_load_lds(
        (const __attribute__((address_space(1))) unsigned int*)g,
        (__attribute__((address_space(3))) unsigned int*)l, 16, 0, 0);
#else
    *reinterpret_cast<uint4*>(l) = *reinterpret_cast<const uint4*>(g);
#endif
}

// 27 B-fragment matrices (ch x tap-row), 32x16 f16 banded-Toeplitz in MFMA fragment order:
// frag[(ch*9+ri)*64 + lane][e], B[k][j], j=lane&15, k=8*(lane>>4)+e, val=merged_w[ch][r][k-8-j].
// Combined bias stored as float at halfs[27*64*8].
__global__ void pack_bfrag(const float* __restrict__ w1, const float* __restrict__ b1,
                           const float* __restrict__ w2, const float* __restrict__ b2,
                           const float* __restrict__ w3, const float* __restrict__ b3,
                           const float* __restrict__ sa, const float* __restrict__ sb,
                           const float* __restrict__ sc_, __half* __restrict__ bfrag) {
    const int tid = threadIdx.x;
    float s[3] = {sa[0], sb[0], sc_[0]};
    const float* wp[3] = {w1, w2, w3};
    for (int idx = tid; idx < 27 * 64; idx += blockDim.x) {
        int mat = idx >> 6;
        int lane = idx & 63;
        int ch = mat / 9, ri = mat % 9;
        int r = kR[ri];
        int j = lane & 15, kg = lane >> 4;
        union { __half h[8]; uint4 u; } v;
#pragma unroll
        for (int e = 0; e < 8; ++e) {
            int k = kg * 8 + e;
            int c = k - 8 - j;
            float a = 0.f;
            if (c >= -8 && c <= 8) {
                for (int b = 0; b < 3; ++b) {
                    int d = 1 << b;
                    if (r % d == 0 && c % d == 0) {
                        int rd = r / d, cd = c / d;
                        if (rd >= -2 && rd <= 2 && cd >= -2 && cd <= 2)
                            a += s[b] * wp[b][ch * 25 + (rd + 2) * 5 + (cd + 2)];
                    }
                }
            }
            v.h[e] = __float2half(a);
        }
        *reinterpret_cast<uint4*>(bfrag + idx * 8) = v.u;
    }
    if (tid == 0)
        *reinterpret_cast<float*>(bfrag + 27 * 64 * 8) = s[0] * b1[0] + s[1] * b2[0] + s[2] * b3[0];
}

// PASS 1: in = f32 x (unpadded), out = f16 ypad (stride SP, reflect-padded cols)
// PASS 2: in = f16 ypad,         out = f32 z   (unpadded)
template <int PASS>
__global__ __launch_bounds__(256, 5) void conv_mfma(const void* __restrict__ xin,
                                                    void* __restrict__ outp,
                                                    const __half* __restrict__ bfrag) {
    __shared__ char lds[LDS_BYTES];

    const int bt = blockIdx.z;
    const int t  = bt % TT;
    const int h0 = blockIdx.y * BTILE;
    const int w0 = blockIdx.x * BTILE;
    const int tid = threadIdx.x;
    const int lane = tid & 63;
    const int wv = tid >> 6;                  // wave id 0..3 = row strip

    const int tprev = (t == 0) ? 1 : t - 1;
    const int tnext = (t == TT - 1) ? TT - 2 : t + 1;
    const int bbase = (bt / TT) * TT;

    const void* fsrc[3];
    if constexpr (PASS == 1) {
        const float* x = (const float*)xin;
        const size_t fs = (size_t)HH * WW;
        fsrc[0] = x + (size_t)(bbase + tprev) * fs;
        fsrc[1] = x + (size_t)bt * fs;
        fsrc[2] = x + (size_t)(bbase + tnext) * fs;
    } else {
        const __half* y = (const __half*)xin;
        const size_t fsP = (size_t)HH * SP;
        fsrc[0] = y + (size_t)(bbase + tprev) * fsP;
        fsrc[1] = y + (size_t)bt * fsP;
        fsrc[2] = y + (size_t)(bbase + tnext) * fsP;
    }

    // ---- STAGE one channel plane into a ping-pong buffer ----
    auto STAGE = [&](int ch, char* buf) {
        if constexpr (PASS == 1) {
            const float* src = (const float*)fsrc[ch];
            for (int k2 = tid; k2 < PROWS * 10; k2 += 256) {
                int row = k2 / 10;
                int c8  = k2 - row * 10;
                int gh = reflect_idx(h0 - 8 + row, HH);
                int gb = w0 - 8 + c8 * 8;
                const float* rp = src + (size_t)gh * WW;
                union { __half h[8]; uint4 u; } cv;
                if (gb >= 0 && gb + 7 < WW) {
                    const float4 v0 = *reinterpret_cast<const float4*>(rp + gb);
                    const float4 v1 = *reinterpret_cast<const float4*>(rp + gb + 4);
                    cv.h[0] = __float2half(v0.x); cv.h[1] = __float2half(v0.y);
                    cv.h[2] = __float2half(v0.z); cv.h[3] = __float2half(v0.w);
                    cv.h[4] = __float2half(v1.x); cv.h[5] = __float2half(v1.y);
                    cv.h[6] = __float2half(v1.z); cv.h[7] = __float2half(v1.w);
                } else {
#pragma unroll
                    for (int e = 0; e < 8; ++e)
                        cv.h[e] = __float2half(rp[reflect_idx(gb + e, WW)]);
                }
                *reinterpret_cast<uint4*>(buf + row * ROWB + c8 * 16) = cv.u;
            }
        } else {
            const __half* src = (const __half*)fsrc[ch];
            for (int c = wv; c < 13; c += 4) {        // 13 x 1024B chunks, wave-uniform
                int byt = c * 1024 + lane * 16;
                if (byt < PLANE_BYTES) {              // tail of chunk 12 masked
                    int row  = byt / ROWB;
                    int colh = (byt - row * ROWB) >> 1;
                    int gh = reflect_idx(h0 - 8 + row, HH);
                    const __half* g = src + (size_t)gh * SP + (w0 + colh); // pad+8 == halo-8
                    async_cp16(g, buf + byt);
                }
            }
        }
    };

    const float bias = *reinterpret_cast<const float*>(bfrag + 27 * 64 * 8);
    f32x4 acc0 = {bias, bias, bias, bias};
    f32x4 acc1 = acc0, acc2 = acc0, acc3 = acc0;

    const int i16 = lane & 15;
    const int kg  = lane >> 4;
    const int aoff = (16 * wv + i16) * ROWB + kg * 16;   // per-thread base within a buffer

    // ---- COMPUTE one channel from a buffer: 9 taps x 4 col strips ----
    auto COMPUTE = [&](int ch, const char* buf) {
        const __half* bp = bfrag + (size_t)ch * 9 * 512 + lane * 8;
        half8 bf[9];
#pragma unroll
        for (int ri = 0; ri < 9; ++ri)
            bf[ri] = *reinterpret_cast<const half8*>(bp + ri * 512);
        const char* aB = buf + aoff;
#pragma unroll
        for (int ri = 0; ri < 9; ++ri) {
            const char* ar = aB + (kR[ri] + 8) * ROWB;   // literal imm per ri
            half8 a0 = *reinterpret_cast<const half8*>(ar);
            half8 a1 = *reinterpret_cast<const half8*>(ar + 32);
            half8 a2 = *reinterpret_cast<const half8*>(ar + 64);
            half8 a3 = *reinterpret_cast<const half8*>(ar + 96);
            __builtin_amdgcn_s_setprio(1);
            acc0 = __builtin_amdgcn_mfma_f32_16x16x32_f16(a0, bf[ri], acc0, 0, 0, 0);
            acc1 = __builtin_amdgcn_mfma_f32_16x16x32_f16(a1, bf[ri], acc1, 0, 0, 0);
            acc2 = __builtin_amdgcn_mfma_f32_16x16x32_f16(a2, bf[ri], acc2, 0, 0, 0);
            acc3 = __builtin_amdgcn_mfma_f32_16x16x32_f16(a3, bf[ri], acc3, 0, 0, 0);
            __builtin_amdgcn_s_setprio(0);
        }
    };

    // ---- 3-channel pipeline: stage(ch+1) overlaps compute(ch), 1 barrier/channel ----
    STAGE(0, lds);                                   // prologue
#pragma unroll 1
    for (int ch = 0; ch < 3; ++ch) {
        if constexpr (PASS == 2)
            asm volatile("s_waitcnt vmcnt(0)" ::: "memory");  // drain STAGE(ch) DMA
        __syncthreads();                             // buf[ch&1] ready; all left compute(ch-1)
        if (ch < 2) STAGE(ch + 1, lds + ((ch + 1) & 1) * PLANE_STRIDE);
        COMPUTE(ch, lds + (ch & 1) * PLANE_STRIDE);
    }

    // ---- Epilogue: tanh; C layout col=lane&15, row=(lane>>4)*4+reg ----
    if constexpr (PASS == 1) {
        __half* yp = (__half*)outp + (size_t)bt * HH * SP;
#pragma unroll
        for (int sc = 0; sc < 4; ++sc) {
            f32x4 a = (sc == 0) ? acc0 : (sc == 1) ? acc1 : (sc == 2) ? acc2 : acc3;
            const int wcol = w0 + sc * 16 + i16;
#pragma unroll
            for (int v2 = 0; v2 < 4; ++v2) {
                float z = a[v2];
                float e = __expf(2.0f * z);
                z = 1.0f - 2.0f / (e + 1.0f);
                __half hz = __float2half(z);
                __half* rb = yp + (size_t)(h0 + 16 * wv + kg * 4 + v2) * SP;
                rb[8 + wcol] = hz;
                if (wcol >= 1 && wcol <= 8)          rb[8 - wcol] = hz;       // left mirror
                else if (wcol >= 503 && wcol <= 510) rb[1030 - wcol] = hz;    // right mirror
            }
        }
    } else {
        float* dst = (float*)outp + (size_t)bt * HH * WW
                   + (size_t)(h0 + 16 * wv + kg * 4) * WW + (w0 + i16);
#pragma unroll
        for (int sc = 0; sc < 4; ++sc) {
            f32x4 a = (sc == 0) ? acc0 : (sc == 1) ? acc1 : (sc == 2) ? acc2 : acc3;
#pragma unroll
            for (int v2 = 0; v2 < 4; ++v2) {
                float z = a[v2];
                float e = __expf(2.0f * z);
                dst[(size_t)v2 * WW + sc * 16] = 1.0f - 2.0f / (e + 1.0f);
            }
        }
    }
}

extern "C" void kernel_launch(void* const* d_in, const int* in_sizes, int n_in,
                              void* d_out, int out_size, void* d_ws, size_t ws_size,
                              hipStream_t stream) {
    const float* x = (const float*)d_in[0];
    char* ws = (char*)d_ws;
    __half* bf1  = (__half*)ws;                        // 27.7 KB
    __half* bf2  = (__half*)(ws + 32768);              // 27.7 KB
    __half* ypad = (__half*)(ws + 65536);              // 64 x 512 x 528 f16 = 34.6 MB

    pack_bfrag<<<1, 256, 0, stream>>>((const float*)d_in[1], (const float*)d_in[2],
                                      (const float*)d_in[3], (const float*)d_in[4],
                                      (const float*)d_in[5], (const float*)d_in[6],
                                      (const float*)d_in[7], (const float*)d_in[8],
                                      (const float*)d_in[9], bf1);
    pack_bfrag<<<1, 256, 0, stream>>>((const float*)d_in[10], (const float*)d_in[11],
                                      (const float*)d_in[12], (const float*)d_in[13],
                                      (const float*)d_in[14], (const float*)d_in[15],
                                      (const float*)d_in[16], (const float*)d_in[17],
                                      (const float*)d_in[18], bf2);

    dim3 grid(WW / BTILE, HH / BTILE, BB * TT);   // 8 x 8 x 64
    conv_mfma<1><<<grid, 256, 0, stream>>>(x, ypad, bf1);
    conv_mfma<2><<<grid, 256, 0, stream>>>(ypad, d_out, bf2);
}